// Round 5
// baseline (192.872 us; speedup 1.0000x reference)
//
#include <hip/hip_runtime.h>
#include <hip/hip_bf16.h>

typedef __hip_bfloat16 bf16;
typedef __attribute__((ext_vector_type(8))) short short8;
typedef __attribute__((ext_vector_type(4))) float floatx4;

#define DEVI __device__ __forceinline__

DEVI float b2f(bf16 v) { return __bfloat162float(v); }
DEVI bf16 f2b(float v) { return __float2bfloat16(v); }
DEVI unsigned short f2bu(float v) {
    bf16 h = __float2bfloat16(v);
    unsigned short u;
    __builtin_memcpy(&u, &h, 2);
    return u;
}
DEVI float sigmoidf_(float z) { return 1.0f / (1.0f + __expf(-z)); }

// Problem constants
// B=8, H=W=56, C=192, WS=4 -> 14x14 windows, 1568 rows (=49*32), ind=3072,
// hid=ncl=256.  ALL inputs/outputs are float32.
//
// MFMA fragment conventions (mfma_f32_16x16x32_bf16, verified R2-R4):
//   A[m][k]: lane = quad*16 + m15 -> m = m15, k = quad*8 + j  (16B contiguous)
//   B[k][n]: lane = quad*16 + n15 -> k = quad*8 + j, n = n15
//   D[m][n]: col n = lane&15, row m = quad*4 + reg
//
// Key algebraic identities used:
//   sigmoid(L) > 0.5  <=>  L > 0      (tm literals need only logit signs)
//   clause = AND over included literals of (lit > 0.5)   (min>tau <=> all>tau)
//   feat = sigmoid(clauses @ (vote_w@W2/16) + b2)        (logits not an output)

// ---------------------------------------------------------------------------
// K0a: inc bitmask.  inc = (inc_w > 0).  mask layout: [word(16)][clause(256)]
__global__ __launch_bounds__(256) void inc_mask_kernel(const float* __restrict__ inc_w,
                                                       unsigned* __restrict__ mask) {
    int wi = blockIdx.x;   // 0..15
    int cl = threadIdx.x;  // 0..255
    unsigned bits = 0u;
    int base = cl * 512 + wi * 32;
#pragma unroll
    for (int b = 0; b < 32; b++) {
        if (inc_w[base + b] > 0.0f) bits |= (1u << b);
    }
    mask[wi * 256 + cl] = bits;
}

// ---------------------------------------------------------------------------
// K0b: vw2 = vote_w @ W2 / 16  (256 x 3072, K=192), written directly as bf16
// B-fragment layout. 16 k per block -> W2 re-read 16x total.
__global__ __launch_bounds__(256) void vw2_kernel(const float* __restrict__ vote_w,
                                                  const float* __restrict__ W2,
                                                  unsigned short* __restrict__ vw2frag) {
    int n = blockIdx.x * 256 + threadIdx.x;  // 0..3071
    int k0 = blockIdx.y * 16;                // 0..255 step 16
    float acc[16];
#pragma unroll
    for (int kk = 0; kk < 16; kk++) acc[kk] = 0.0f;
    for (int j = 0; j < 192; j++) {
        float w = W2[j * 3072 + n];
#pragma unroll
        for (int kk = 0; kk < 16; kk++) {
            acc[kk] = fmaf(vote_w[(k0 + kk) * 192 + j], w, acc[kk]);  // uniform -> s_load
        }
    }
    int nb = n >> 4;
#pragma unroll
    for (int kk = 0; kk < 16; kk++) {
        int k = k0 + kk;
        int lane = ((k >> 3) & 3) * 16 + (n & 15);
        int off = ((nb * 8 + (k >> 5)) * 64 + lane) * 8 + (k & 7);
        vw2frag[off] = f2bu(acc[kk] * 0.0625f);  // 1/sqrt(256)
    }
}

// ---------------------------------------------------------------------------
// K0c: repack W1 (3072x256 f32) into bf16 B-fragment layout, one 1KB fragment
// per wave -> fully coalesced 16B/lane stores.  1536 fragments, 384 blocks.
__global__ __launch_bounds__(256) void w1frag_kernel(const float* __restrict__ W1,
                                                     unsigned short* __restrict__ w1frag) {
    int t = threadIdx.x;
    int lane = t & 63;
    int fid = blockIdx.x * 4 + (t >> 6);  // = nb*96 + kb
    int nb = fid / 96;
    int kb = fid - nb * 96;
    int n = nb * 16 + (lane & 15);
    int k = kb * 32 + (lane >> 4) * 8;
    short8 v;
#pragma unroll
    for (int j = 0; j < 8; j++) {
        v[j] = (short)f2bu(W1[(k + j) * 256 + n]);
    }
    *reinterpret_cast<short8*>(w1frag + ((size_t)fid * 64 + lane) * 8) = v;
}

// ---------------------------------------------------------------------------
// K1: LayerNorm + roll(-2,-2) + window partition -> win (1568 x 3072) bf16.
// 4 pixels per block (one per wave).
__global__ __launch_bounds__(256) void ln_win_kernel(const float* __restrict__ x,
                                                     const float* __restrict__ gamma,
                                                     const float* __restrict__ beta,
                                                     bf16* __restrict__ win) {
    int blk = blockIdx.x * 4 + (threadIdx.x >> 6);  // b*3136 + h'*56 + w'
    int w_ = blk % 56;
    int t2 = blk / 56;
    int h_ = t2 % 56;
    int b = t2 / 56;
    int hs = h_ + 2; if (hs >= 56) hs -= 56;
    int ws = w_ + 2; if (ws >= 56) ws -= 56;
    const float* xp = x + (((b * 56 + hs) * 56 + ws) * 192);
    int t = threadIdx.x & 63;
    float v0 = xp[t];
    float v1 = xp[t + 64];
    float v2 = xp[t + 128];
    float s = v0 + v1 + v2;
    float sq = v0 * v0 + v1 * v1 + v2 * v2;
#pragma unroll
    for (int m = 1; m < 64; m <<= 1) {
        s += __shfl_xor(s, m, 64);
        sq += __shfl_xor(sq, m, 64);
    }
    float mean = s * (1.0f / 192.0f);
    float var = sq * (1.0f / 192.0f) - mean * mean;
    float inv = rsqrtf(var + 1e-5f);
    int row = b * 196 + (h_ >> 2) * 14 + (w_ >> 2);
    int fb = ((h_ & 3) * 4 + (w_ & 3)) * 192;
    bf16* wp = win + row * 3072 + fb;
    wp[t]       = f2b((v0 - mean) * inv * gamma[t]       + beta[t]);
    wp[t + 64]  = f2b((v1 - mean) * inv * gamma[t + 64]  + beta[t + 64]);
    wp[t + 128] = f2b((v2 - mean) * inv * gamma[t + 128] + beta[t + 128]);
}

// ---------------------------------------------------------------------------
// K2: raw logit partials of win @ W1.  M=1568, N=256, K=3072, 4-way K-split.
// grid (49 m, 2 n, 4 k) = 392 blocks; 4 waves = 2m x 2n; wave tile 16m x 64n
// (4 acc tiles) -> 1.25 loads/MFMA.  No bias/sigmoid here (sign-only consumer).
__global__ __launch_bounds__(256) void gemm1_mfma(const bf16* __restrict__ win,
                                                  const unsigned short* __restrict__ w1frag,
                                                  float* __restrict__ part) {
    int t = threadIdx.x;
    int wave = t >> 6;
    int lane = t & 63;
    int quad = lane >> 4;
    int mlo = lane & 15;
    int wm = wave & 1;
    int wn = wave >> 1;
    int m0 = blockIdx.x * 32 + wm * 16;
    int nb0 = blockIdx.y * 8 + wn * 4;   // 16-wide n-tile base (0..15)
    int kz = blockIdx.z;                 // 0..3, covers k in [kz*768, kz*768+768)

    const bf16* ap = win + (m0 + mlo) * 3072 + kz * 768 + quad * 8;
    const unsigned short* bp = w1frag + lane * 8;
    int kb0 = kz * 24;

    floatx4 acc[4];
#pragma unroll
    for (int i = 0; i < 4; i++) acc[i] = (floatx4){0.f, 0.f, 0.f, 0.f};

#pragma unroll 4
    for (int kb = 0; kb < 24; kb++) {
        short8 a = *reinterpret_cast<const short8*>(ap + kb * 32);
#pragma unroll
        for (int i = 0; i < 4; i++) {
            short8 b = *reinterpret_cast<const short8*>(
                bp + ((size_t)((nb0 + i) * 96 + kb0 + kb)) * 512);
            acc[i] = __builtin_amdgcn_mfma_f32_16x16x32_bf16(a, b, acc[i], 0, 0, 0);
        }
    }

    float* pp = part + kz * 401408;
#pragma unroll
    for (int i = 0; i < 4; i++) {
        int n_g = (nb0 + i) * 16 + mlo;
#pragma unroll
        for (int r = 0; r < 4; r++) {
            int m_g = m0 + quad * 4 + r;
            pp[m_g * 256 + n_g] = acc[i][r];
        }
    }
}

// ---------------------------------------------------------------------------
// K3: clauses via bitwise AND over logit signs.  One block per window row.
// lit t included-true  <=> logit > 0;  lit 256+t  <=> logit < 0.
__global__ __launch_bounds__(256) void tm_kernel(const float* __restrict__ part,
                                                 const float* __restrict__ b1,
                                                 const unsigned* __restrict__ mask,
                                                 float* __restrict__ cl_out,
                                                 bf16* __restrict__ clauses_bf,
                                                 float* __restrict__ sum_out) {
    __shared__ unsigned g_s[16];
    __shared__ float red[4];
    int row = blockIdx.x;
    int t = threadIdx.x;
    int wave = t >> 6;
    int lane = t & 63;
    int idx = row * 256 + t;
    float L = part[idx] + part[401408 + idx] + part[802816 + idx] +
              part[1204224 + idx] + b1[t];
    unsigned long long bhi = __ballot(L > 0.0f);  // lit t
    unsigned long long blo = __ballot(L < 0.0f);  // lit 256+t
    if (lane == 0) {
        g_s[wave * 2]         = (unsigned)bhi;
        g_s[wave * 2 + 1]     = (unsigned)(bhi >> 32);
        g_s[8 + wave * 2]     = (unsigned)blo;
        g_s[8 + wave * 2 + 1] = (unsigned)(blo >> 32);
    }
    __syncthreads();
    unsigned ok = 1u;
#pragma unroll
    for (int w = 0; w < 16; w++) {
        unsigned viol = (~g_s[w]) & mask[w * 256 + t];
        ok &= (viol == 0u) ? 1u : 0u;
    }
    float hard = (float)ok;
    cl_out[idx] = hard;
    clauses_bf[idx] = f2b(hard);
    unsigned long long cb = __ballot(ok != 0u);
    if (lane == 0) red[wave] = (float)__popcll(cb);
    __syncthreads();
    if (t == 0) sum_out[row] = (red[0] + red[1] + red[2] + red[3]) * (1.0f / 256.0f);
}

// ---------------------------------------------------------------------------
// K4: fused  feat = sigmoid(clauses @ vw2 + b2)  +  window-reverse + roll(+2,+2)
// + gated residual -> out.  M=1568, N=3072, K=256.  grid (49, 24), 4 waves
// 2m x 2n, wave tile 16m x 64n (4 acc tiles).  feat never materialized.
__global__ __launch_bounds__(256) void gemm2_out(const bf16* __restrict__ clauses_bf,
                                                 const unsigned short* __restrict__ vw2frag,
                                                 const float* __restrict__ b2v,
                                                 const float* __restrict__ x,
                                                 const float* __restrict__ gate,
                                                 float* __restrict__ out) {
    int t = threadIdx.x;
    int wave = t >> 6;
    int lane = t & 63;
    int quad = lane >> 4;
    int mlo = lane & 15;
    int wm = wave & 1;
    int wn = wave >> 1;
    int m0 = blockIdx.x * 32 + wm * 16;
    int nb0 = blockIdx.y * 8 + wn * 4;  // 16-wide n-tile base (0..191)

    const bf16* ap = clauses_bf + (m0 + mlo) * 256 + quad * 8;
    const unsigned short* bp = vw2frag + lane * 8;

    floatx4 acc[4];
#pragma unroll
    for (int i = 0; i < 4; i++) acc[i] = (floatx4){0.f, 0.f, 0.f, 0.f};

#pragma unroll
    for (int kb = 0; kb < 8; kb++) {
        short8 a = *reinterpret_cast<const short8*>(ap + kb * 32);
#pragma unroll
        for (int i = 0; i < 4; i++) {
            short8 b = *reinterpret_cast<const short8*>(
                bp + ((size_t)((nb0 + i) * 8 + kb)) * 512);
            acc[i] = __builtin_amdgcn_mfma_f32_16x16x32_bf16(a, b, acc[i], 0, 0, 0);
        }
    }

    float g = sigmoidf_(gate[0]);
    // per-r inverse window mapping: m_g -> (batch, window-h, window-w)
    int bq[4], wh[4], ww[4];
#pragma unroll
    for (int r = 0; r < 4; r++) {
        int m_g = m0 + quad * 4 + r;
        bq[r] = m_g / 196;
        int rem = m_g - bq[r] * 196;
        wh[r] = rem / 14;
        ww[r] = rem - wh[r] * 14;
    }
#pragma unroll
    for (int i = 0; i < 4; i++) {
        int n_g = (nb0 + i) * 16 + mlo;
        int cell = n_g / 192;           // 0..15 (position inside 4x4 window)
        int ch = n_g - cell * 192;      // channel
        int cellh = cell >> 2;
        int cellw = cell & 3;
        float bb = b2v[n_g];
#pragma unroll
        for (int r = 0; r < 4; r++) {
            int hh = wh[r] * 4 + cellh + 2; if (hh >= 56) hh -= 56;  // roll(+2)
            int wc = ww[r] * 4 + cellw + 2; if (wc >= 56) wc -= 56;
            int gid = ((bq[r] * 56 + hh) * 56 + wc) * 192 + ch;
            float mv = sigmoidf_(acc[i][r] + bb);
            out[gid] = x[gid] + g * mv + (1.0f - g) * sigmoidf_(mv);
        }
    }
}

// ---------------------------------------------------------------------------
extern "C" void kernel_launch(void* const* d_in, const int* in_sizes, int n_in,
                              void* d_out, int out_size, void* d_ws, size_t ws_size,
                              hipStream_t stream) {
    const float* x      = (const float*)d_in[0];
    const float* gamma  = (const float*)d_in[1];
    const float* beta   = (const float*)d_in[2];
    const float* W1     = (const float*)d_in[3];
    const float* b1     = (const float*)d_in[4];
    const float* inc_w  = (const float*)d_in[5];
    const float* vote_w = (const float*)d_in[6];
    const float* W2     = (const float*)d_in[7];
    const float* b2v    = (const float*)d_in[8];
    const float* gate   = (const float*)d_in[9];

    char* ws = (char*)d_ws;
    // workspace carve (bytes), total ~20.0 MB:
    bf16*           win        = (bf16*)(ws + 0);                  // 9,633,792
    float*          part       = (float*)(ws + 9633792);           // 6,422,528 (4x 1568*256*4)
    unsigned short* w1frag     = (unsigned short*)(ws + 16056320); // 1,572,864
    unsigned short* vw2frag    = (unsigned short*)(ws + 17629184); // 1,572,864
    bf16*           clauses_bf = (bf16*)(ws + 19202048);           //   802,816
    unsigned*       mask       = (unsigned*)(ws + 20004864);       //    16,384

    float* out     = (float*)d_out;
    float* cl_out  = out + 4816896;            // clauses: 1568*256
    float* sum_out = cl_out + 401408;          // summary: 1568

    inc_mask_kernel<<<16, 256, 0, stream>>>(inc_w, mask);
    vw2_kernel<<<dim3(12, 16), 256, 0, stream>>>(vote_w, W2, vw2frag);
    w1frag_kernel<<<384, 256, 0, stream>>>(W1, w1frag);
    ln_win_kernel<<<6272, 256, 0, stream>>>(x, gamma, beta, win);
    gemm1_mfma<<<dim3(49, 2, 4), 256, 0, stream>>>(win, w1frag, part);
    tm_kernel<<<1568, 256, 0, stream>>>(part, b1, mask, cl_out, clauses_bf, sum_out);
    gemm2_out<<<dim3(49, 24), 256, 0, stream>>>(clauses_bf, vw2frag, b2v, x, gate, out);
}

// Round 6
// 147.424 us; speedup vs baseline: 1.3083x; 1.3083x over previous
//
#include <hip/hip_runtime.h>
#include <hip/hip_bf16.h>

typedef __hip_bfloat16 bf16;
typedef __attribute__((ext_vector_type(8))) short short8;
typedef __attribute__((ext_vector_type(4))) float floatx4;

#define DEVI __device__ __forceinline__

DEVI float b2f(bf16 v) { return __bfloat162float(v); }
DEVI bf16 f2b(float v) { return __float2bfloat16(v); }
DEVI unsigned short f2bu(float v) {
    bf16 h = __float2bfloat16(v);
    unsigned short u;
    __builtin_memcpy(&u, &h, 2);
    return u;
}
DEVI float sigmoidf_(float z) { return 1.0f / (1.0f + __expf(-z)); }

// Problem constants
// B=8, H=W=56, C=192, WS=4 -> 14x14 windows, 1568 rows (=49*32), ind=3072,
// hid=ncl=256.  ALL inputs/outputs are float32.
//
// MFMA fragment conventions (mfma_f32_16x16x32_bf16, verified R2-R5):
//   A[m][k]: lane = quad*16 + m15 -> m = m15, k = quad*8 + j  (16B contiguous)
//   B[k][n]: lane = quad*16 + n15 -> k = quad*8 + j, n = n15
//   D[m][n]: col n = lane&15, row m = quad*4 + reg
//
// Key algebraic identities used:
//   sigmoid(L) > 0.5  <=>  L > 0      (tm literals need only logit signs)
//   clause = AND over included literals of (lit > 0.5)   (min>tau <=> all>tau)
//   feat = sigmoid(clauses @ (vote_w@W2/16) + b2)        (logits not an output)

// ---------------------------------------------------------------------------
// K0a: inc bitmask.  inc = (inc_w > 0).  mask layout: [word(16)][clause(256)]
__global__ __launch_bounds__(256) void inc_mask_kernel(const float* __restrict__ inc_w,
                                                       unsigned* __restrict__ mask) {
    int wi = blockIdx.x;   // 0..15
    int cl = threadIdx.x;  // 0..255
    unsigned bits = 0u;
    int base = cl * 512 + wi * 32;
#pragma unroll
    for (int b = 0; b < 32; b++) {
        if (inc_w[base + b] > 0.0f) bits |= (1u << b);
    }
    mask[wi * 256 + cl] = bits;
}

// ---------------------------------------------------------------------------
// K0b: vw2 = vote_w @ W2 / 16  (M=256, N=3072, K=192) via MFMA, output written
// directly in bf16 B-fragment layout for gemm2.  Wave tile 16m x 16n; block =
// 4 waves over 64 n; grid (16 m, 48 n) = 768 blocks (3 blocks/CU).  K = 6
// MFMA steps (vs 192 serial scalar loads in R5's latency-bound version).
__global__ __launch_bounds__(256) void vw2_mfma(const float* __restrict__ vote_w,
                                                const float* __restrict__ W2,
                                                unsigned short* __restrict__ vw2frag) {
    int t = threadIdx.x;
    int wave = t >> 6;
    int lane = t & 63;
    int quad = lane >> 4;
    int l15 = lane & 15;
    int mt = blockIdx.x;                 // 0..15: 16-wide k_out tile
    int nt = blockIdx.y * 4 + wave;      // 0..191: 16-wide n tile

    const float* ap = vote_w + (mt * 16 + l15) * 192 + quad * 8;  // 8 contiguous f32
    const float* bp = W2 + (quad * 8) * 3072 + nt * 16 + l15;     // 8 x stride-3072

    floatx4 acc = {0.f, 0.f, 0.f, 0.f};
#pragma unroll
    for (int kb = 0; kb < 6; kb++) {
        float4 a0 = *reinterpret_cast<const float4*>(ap + kb * 32);
        float4 a1 = *reinterpret_cast<const float4*>(ap + kb * 32 + 4);
        short8 a, b;
        a[0] = (short)f2bu(a0.x); a[1] = (short)f2bu(a0.y);
        a[2] = (short)f2bu(a0.z); a[3] = (short)f2bu(a0.w);
        a[4] = (short)f2bu(a1.x); a[5] = (short)f2bu(a1.y);
        a[6] = (short)f2bu(a1.z); a[7] = (short)f2bu(a1.w);
#pragma unroll
        for (int j = 0; j < 8; j++) {
            b[j] = (short)f2bu(bp[(kb * 32 + j) * 3072]);
        }
        acc = __builtin_amdgcn_mfma_f32_16x16x32_bf16(a, b, acc, 0, 0, 0);
    }
#pragma unroll
    for (int r = 0; r < 4; r++) {
        int k = mt * 16 + quad * 4 + r;               // k index of gemm2 (0..255)
        int off = ((nt * 8 + (k >> 5)) * 64 + ((k >> 3) & 3) * 16 + l15) * 8 + (k & 7);
        vw2frag[off] = f2bu(acc[r] * 0.0625f);        // 1/sqrt(256)
    }
}

// ---------------------------------------------------------------------------
// K0c: repack W1 (3072x256 f32) into bf16 B-fragment layout, one 1KB fragment
// per wave -> fully coalesced 16B/lane stores.  1536 fragments, 384 blocks.
__global__ __launch_bounds__(256) void w1frag_kernel(const float* __restrict__ W1,
                                                     unsigned short* __restrict__ w1frag) {
    int t = threadIdx.x;
    int lane = t & 63;
    int fid = blockIdx.x * 4 + (t >> 6);  // = nb*96 + kb
    int nb = fid / 96;
    int kb = fid - nb * 96;
    int n = nb * 16 + (lane & 15);
    int k = kb * 32 + (lane >> 4) * 8;
    short8 v;
#pragma unroll
    for (int j = 0; j < 8; j++) {
        v[j] = (short)f2bu(W1[(k + j) * 256 + n]);
    }
    *reinterpret_cast<short8*>(w1frag + ((size_t)fid * 64 + lane) * 8) = v;
}

// ---------------------------------------------------------------------------
// K1: LayerNorm + roll(-2,-2) + window partition -> win (1568 x 3072) bf16.
// 4 pixels per block (one per wave).
__global__ __launch_bounds__(256) void ln_win_kernel(const float* __restrict__ x,
                                                     const float* __restrict__ gamma,
                                                     const float* __restrict__ beta,
                                                     bf16* __restrict__ win) {
    int blk = blockIdx.x * 4 + (threadIdx.x >> 6);  // b*3136 + h'*56 + w'
    int w_ = blk % 56;
    int t2 = blk / 56;
    int h_ = t2 % 56;
    int b = t2 / 56;
    int hs = h_ + 2; if (hs >= 56) hs -= 56;
    int ws = w_ + 2; if (ws >= 56) ws -= 56;
    const float* xp = x + (((b * 56 + hs) * 56 + ws) * 192);
    int t = threadIdx.x & 63;
    float v0 = xp[t];
    float v1 = xp[t + 64];
    float v2 = xp[t + 128];
    float s = v0 + v1 + v2;
    float sq = v0 * v0 + v1 * v1 + v2 * v2;
#pragma unroll
    for (int m = 1; m < 64; m <<= 1) {
        s += __shfl_xor(s, m, 64);
        sq += __shfl_xor(sq, m, 64);
    }
    float mean = s * (1.0f / 192.0f);
    float var = sq * (1.0f / 192.0f) - mean * mean;
    float inv = rsqrtf(var + 1e-5f);
    int row = b * 196 + (h_ >> 2) * 14 + (w_ >> 2);
    int fb = ((h_ & 3) * 4 + (w_ & 3)) * 192;
    bf16* wp = win + row * 3072 + fb;
    wp[t]       = f2b((v0 - mean) * inv * gamma[t]       + beta[t]);
    wp[t + 64]  = f2b((v1 - mean) * inv * gamma[t + 64]  + beta[t + 64]);
    wp[t + 128] = f2b((v2 - mean) * inv * gamma[t + 128] + beta[t + 128]);
}

// ---------------------------------------------------------------------------
// K2: raw logit partials of win @ W1.  M=1568, N=256, K=3072, 4-way K-split.
// grid (49 m, 2 n, 4 k) = 392 blocks; 4 waves = 2m x 2n; wave tile 16m x 64n
// (4 acc tiles) -> 1.25 loads/MFMA.  No bias/sigmoid here (sign-only consumer).
__global__ __launch_bounds__(256) void gemm1_mfma(const bf16* __restrict__ win,
                                                  const unsigned short* __restrict__ w1frag,
                                                  float* __restrict__ part) {
    int t = threadIdx.x;
    int wave = t >> 6;
    int lane = t & 63;
    int quad = lane >> 4;
    int mlo = lane & 15;
    int wm = wave & 1;
    int wn = wave >> 1;
    int m0 = blockIdx.x * 32 + wm * 16;
    int nb0 = blockIdx.y * 8 + wn * 4;   // 16-wide n-tile base (0..15)
    int kz = blockIdx.z;                 // 0..3, covers k in [kz*768, kz*768+768)

    const bf16* ap = win + (m0 + mlo) * 3072 + kz * 768 + quad * 8;
    const unsigned short* bp = w1frag + lane * 8;
    int kb0 = kz * 24;

    floatx4 acc[4];
#pragma unroll
    for (int i = 0; i < 4; i++) acc[i] = (floatx4){0.f, 0.f, 0.f, 0.f};

#pragma unroll 4
    for (int kb = 0; kb < 24; kb++) {
        short8 a = *reinterpret_cast<const short8*>(ap + kb * 32);
#pragma unroll
        for (int i = 0; i < 4; i++) {
            short8 b = *reinterpret_cast<const short8*>(
                bp + ((size_t)((nb0 + i) * 96 + kb0 + kb)) * 512);
            acc[i] = __builtin_amdgcn_mfma_f32_16x16x32_bf16(a, b, acc[i], 0, 0, 0);
        }
    }

    float* pp = part + kz * 401408;
#pragma unroll
    for (int i = 0; i < 4; i++) {
        int n_g = (nb0 + i) * 16 + mlo;
#pragma unroll
        for (int r = 0; r < 4; r++) {
            int m_g = m0 + quad * 4 + r;
            pp[m_g * 256 + n_g] = acc[i][r];
        }
    }
}

// ---------------------------------------------------------------------------
// K3: clauses via bitwise AND over logit signs.  One block per window row.
// lit t included-true  <=> logit > 0;  lit 256+t  <=> logit < 0.
__global__ __launch_bounds__(256) void tm_kernel(const float* __restrict__ part,
                                                 const float* __restrict__ b1,
                                                 const unsigned* __restrict__ mask,
                                                 float* __restrict__ cl_out,
                                                 bf16* __restrict__ clauses_bf,
                                                 float* __restrict__ sum_out) {
    __shared__ unsigned g_s[16];
    __shared__ float red[4];
    int row = blockIdx.x;
    int t = threadIdx.x;
    int wave = t >> 6;
    int lane = t & 63;
    int idx = row * 256 + t;
    float L = part[idx] + part[401408 + idx] + part[802816 + idx] +
              part[1204224 + idx] + b1[t];
    unsigned long long bhi = __ballot(L > 0.0f);  // lit t
    unsigned long long blo = __ballot(L < 0.0f);  // lit 256+t
    if (lane == 0) {
        g_s[wave * 2]         = (unsigned)bhi;
        g_s[wave * 2 + 1]     = (unsigned)(bhi >> 32);
        g_s[8 + wave * 2]     = (unsigned)blo;
        g_s[8 + wave * 2 + 1] = (unsigned)(blo >> 32);
    }
    __syncthreads();
    unsigned ok = 1u;
#pragma unroll
    for (int w = 0; w < 16; w++) {
        unsigned viol = (~g_s[w]) & mask[w * 256 + t];
        ok &= (viol == 0u) ? 1u : 0u;
    }
    float hard = (float)ok;
    cl_out[idx] = hard;
    clauses_bf[idx] = f2b(hard);
    unsigned long long cb = __ballot(ok != 0u);
    if (lane == 0) red[wave] = (float)__popcll(cb);
    __syncthreads();
    if (t == 0) sum_out[row] = (red[0] + red[1] + red[2] + red[3]) * (1.0f / 256.0f);
}

// ---------------------------------------------------------------------------
// K4: fused  feat = sigmoid(clauses @ vw2 + b2)  +  window-reverse + roll(+2,+2)
// + gated residual -> out.  M=1568, N=3072, K=256.  grid (49, 24), 4 waves
// 2m x 2n, wave tile 16m x 64n (4 acc tiles).  feat never materialized.
__global__ __launch_bounds__(256) void gemm2_out(const bf16* __restrict__ clauses_bf,
                                                 const unsigned short* __restrict__ vw2frag,
                                                 const float* __restrict__ b2v,
                                                 const float* __restrict__ x,
                                                 const float* __restrict__ gate,
                                                 float* __restrict__ out) {
    int t = threadIdx.x;
    int wave = t >> 6;
    int lane = t & 63;
    int quad = lane >> 4;
    int mlo = lane & 15;
    int wm = wave & 1;
    int wn = wave >> 1;
    int m0 = blockIdx.x * 32 + wm * 16;
    int nb0 = blockIdx.y * 8 + wn * 4;  // 16-wide n-tile base (0..191)

    const bf16* ap = clauses_bf + (m0 + mlo) * 256 + quad * 8;
    const unsigned short* bp = vw2frag + lane * 8;

    floatx4 acc[4];
#pragma unroll
    for (int i = 0; i < 4; i++) acc[i] = (floatx4){0.f, 0.f, 0.f, 0.f};

#pragma unroll
    for (int kb = 0; kb < 8; kb++) {
        short8 a = *reinterpret_cast<const short8*>(ap + kb * 32);
#pragma unroll
        for (int i = 0; i < 4; i++) {
            short8 b = *reinterpret_cast<const short8*>(
                bp + ((size_t)((nb0 + i) * 8 + kb)) * 512);
            acc[i] = __builtin_amdgcn_mfma_f32_16x16x32_bf16(a, b, acc[i], 0, 0, 0);
        }
    }

    float g = sigmoidf_(gate[0]);
    // per-r inverse window mapping: m_g -> (batch, window-h, window-w)
    int bq[4], wh[4], ww[4];
#pragma unroll
    for (int r = 0; r < 4; r++) {
        int m_g = m0 + quad * 4 + r;
        bq[r] = m_g / 196;
        int rem = m_g - bq[r] * 196;
        wh[r] = rem / 14;
        ww[r] = rem - wh[r] * 14;
    }
#pragma unroll
    for (int i = 0; i < 4; i++) {
        int n_g = (nb0 + i) * 16 + mlo;
        int cell = n_g / 192;           // 0..15 (position inside 4x4 window)
        int ch = n_g - cell * 192;      // channel
        int cellh = cell >> 2;
        int cellw = cell & 3;
        float bb = b2v[n_g];
#pragma unroll
        for (int r = 0; r < 4; r++) {
            int hh = wh[r] * 4 + cellh + 2; if (hh >= 56) hh -= 56;  // roll(+2)
            int wc = ww[r] * 4 + cellw + 2; if (wc >= 56) wc -= 56;
            int gid = ((bq[r] * 56 + hh) * 56 + wc) * 192 + ch;
            float mv = sigmoidf_(acc[i][r] + bb);
            out[gid] = x[gid] + g * mv + (1.0f - g) * sigmoidf_(mv);
        }
    }
}

// ---------------------------------------------------------------------------
extern "C" void kernel_launch(void* const* d_in, const int* in_sizes, int n_in,
                              void* d_out, int out_size, void* d_ws, size_t ws_size,
                              hipStream_t stream) {
    const float* x      = (const float*)d_in[0];
    const float* gamma  = (const float*)d_in[1];
    const float* beta   = (const float*)d_in[2];
    const float* W1     = (const float*)d_in[3];
    const float* b1     = (const float*)d_in[4];
    const float* inc_w  = (const float*)d_in[5];
    const float* vote_w = (const float*)d_in[6];
    const float* W2     = (const float*)d_in[7];
    const float* b2v    = (const float*)d_in[8];
    const float* gate   = (const float*)d_in[9];

    char* ws = (char*)d_ws;
    // workspace carve (bytes), total ~20.0 MB:
    bf16*           win        = (bf16*)(ws + 0);                  // 9,633,792
    float*          part       = (float*)(ws + 9633792);           // 6,422,528 (4x 1568*256*4)
    unsigned short* w1frag     = (unsigned short*)(ws + 16056320); // 1,572,864
    unsigned short* vw2frag    = (unsigned short*)(ws + 17629184); // 1,572,864
    bf16*           clauses_bf = (bf16*)(ws + 19202048);           //   802,816
    unsigned*       mask       = (unsigned*)(ws + 20004864);       //    16,384

    float* out     = (float*)d_out;
    float* cl_out  = out + 4816896;            // clauses: 1568*256
    float* sum_out = cl_out + 401408;          // summary: 1568

    inc_mask_kernel<<<16, 256, 0, stream>>>(inc_w, mask);
    vw2_mfma<<<dim3(16, 48), 256, 0, stream>>>(vote_w, W2, vw2frag);
    w1frag_kernel<<<384, 256, 0, stream>>>(W1, w1frag);
    ln_win_kernel<<<6272, 256, 0, stream>>>(x, gamma, beta, win);
    gemm1_mfma<<<dim3(49, 2, 4), 256, 0, stream>>>(win, w1frag, part);
    tm_kernel<<<1568, 256, 0, stream>>>(part, b1, mask, cl_out, clauses_bf, sum_out);
    gemm2_out<<<dim3(49, 24), 256, 0, stream>>>(clauses_bf, vw2frag, b2v, x, gate, out);
}

// Round 7
// 139.645 us; speedup vs baseline: 1.3812x; 1.0557x over previous
//
#include <hip/hip_runtime.h>
#include <hip/hip_bf16.h>

typedef __hip_bfloat16 bf16;
typedef __attribute__((ext_vector_type(8))) short short8;
typedef __attribute__((ext_vector_type(4))) float floatx4;

#define DEVI __device__ __forceinline__

DEVI float b2f(bf16 v) { return __bfloat162float(v); }
DEVI bf16 f2b(float v) { return __float2bfloat16(v); }
DEVI unsigned short f2bu(float v) {
    bf16 h = __float2bfloat16(v);
    unsigned short u;
    __builtin_memcpy(&u, &h, 2);
    return u;
}
DEVI float sigmoidf_(float z) { return 1.0f / (1.0f + __expf(-z)); }

// Problem constants
// B=8, H=W=56, C=192, WS=4 -> 14x14 windows, 1568 rows (=49*32), ind=3072,
// hid=ncl=256.  ALL inputs/outputs are float32.
//
// MFMA fragment conventions (mfma_f32_16x16x32_bf16, verified R2-R6):
//   A[m][k]: lane = quad*16 + m15 -> m = m15, k = quad*8 + j  (16B contiguous)
//   B[k][n]: lane = quad*16 + n15 -> k = quad*8 + j, n = n15
//   D[m][n]: col n = lane&15, row m = quad*4 + reg
//
// Key algebraic identities used:
//   sigmoid(L) > 0.5  <=>  L > 0      (tm literals need only logit signs)
//   clause = AND over included literals of (lit > 0.5)   (min>tau <=> all>tau)
//   feat = sigmoid(clauses @ (vote_w@W2/16) + b2)        (logits not an output)

// ---------------------------------------------------------------------------
// K0 (merged pre): block-ranged fusion of 4 independent preprocessing stages.
//   [0, 6272)     : LayerNorm + roll(-2,-2) + window partition -> win (bf16)
//   [6272, 7040)  : vw2 = vote_w @ W2 / 16 via MFMA -> vw2frag (bf16 B-frag)
//   [7040, 7424)  : W1 f32 -> bf16 B-fragment repack -> w1frag
//   [7424, 7440)  : inc bitmask (inc = inc_w > 0) -> mask[word(16)][clause(256)]
__global__ __launch_bounds__(256) void pre_kernel(const float* __restrict__ x,
                                                  const float* __restrict__ gamma,
                                                  const float* __restrict__ beta,
                                                  const float* __restrict__ vote_w,
                                                  const float* __restrict__ W2,
                                                  const float* __restrict__ W1,
                                                  const float* __restrict__ inc_w,
                                                  bf16* __restrict__ win,
                                                  unsigned short* __restrict__ vw2frag,
                                                  unsigned short* __restrict__ w1frag,
                                                  unsigned* __restrict__ mask) {
    int bx = blockIdx.x;
    int t = threadIdx.x;
    if (bx < 6272) {
        // ---- LayerNorm + shift + window partition (1 pixel per wave) ----
        int blk = bx * 4 + (t >> 6);  // b*3136 + h'*56 + w'  (rolled coords)
        int w_ = blk % 56;
        int t2 = blk / 56;
        int h_ = t2 % 56;
        int b = t2 / 56;
        int hs = h_ + 2; if (hs >= 56) hs -= 56;
        int ws = w_ + 2; if (ws >= 56) ws -= 56;
        const float* xp = x + (((b * 56 + hs) * 56 + ws) * 192);
        int l = t & 63;
        float v0 = xp[l];
        float v1 = xp[l + 64];
        float v2 = xp[l + 128];
        float s = v0 + v1 + v2;
        float sq = v0 * v0 + v1 * v1 + v2 * v2;
#pragma unroll
        for (int m = 1; m < 64; m <<= 1) {
            s += __shfl_xor(s, m, 64);
            sq += __shfl_xor(sq, m, 64);
        }
        float mean = s * (1.0f / 192.0f);
        float var = sq * (1.0f / 192.0f) - mean * mean;
        float inv = rsqrtf(var + 1e-5f);
        int row = b * 196 + (h_ >> 2) * 14 + (w_ >> 2);
        int fb = ((h_ & 3) * 4 + (w_ & 3)) * 192;
        bf16* wp = win + row * 3072 + fb;
        wp[l]       = f2b((v0 - mean) * inv * gamma[l]       + beta[l]);
        wp[l + 64]  = f2b((v1 - mean) * inv * gamma[l + 64]  + beta[l + 64]);
        wp[l + 128] = f2b((v2 - mean) * inv * gamma[l + 128] + beta[l + 128]);
    } else if (bx < 7040) {
        // ---- vw2 MFMA: M=256(k_out), N=3072, K=192 ----
        int bid = bx - 6272;           // 0..767
        int wave = t >> 6;
        int lane = t & 63;
        int quad = lane >> 4;
        int l15 = lane & 15;
        int mt = bid & 15;             // 16-wide k_out tile
        int nt = (bid >> 4) * 4 + wave; // 0..191: 16-wide n tile

        const float* ap = vote_w + (mt * 16 + l15) * 192 + quad * 8;
        const float* bp = W2 + (quad * 8) * 3072 + nt * 16 + l15;

        floatx4 acc = {0.f, 0.f, 0.f, 0.f};
#pragma unroll
        for (int kb = 0; kb < 6; kb++) {
            float4 a0 = *reinterpret_cast<const float4*>(ap + kb * 32);
            float4 a1 = *reinterpret_cast<const float4*>(ap + kb * 32 + 4);
            short8 a, b;
            a[0] = (short)f2bu(a0.x); a[1] = (short)f2bu(a0.y);
            a[2] = (short)f2bu(a0.z); a[3] = (short)f2bu(a0.w);
            a[4] = (short)f2bu(a1.x); a[5] = (short)f2bu(a1.y);
            a[6] = (short)f2bu(a1.z); a[7] = (short)f2bu(a1.w);
#pragma unroll
            for (int j = 0; j < 8; j++) {
                b[j] = (short)f2bu(bp[(kb * 32 + j) * 3072]);
            }
            acc = __builtin_amdgcn_mfma_f32_16x16x32_bf16(a, b, acc, 0, 0, 0);
        }
#pragma unroll
        for (int r = 0; r < 4; r++) {
            int k = mt * 16 + quad * 4 + r;  // gemm2 k index (0..255)
            int off = ((nt * 8 + (k >> 5)) * 64 + ((k >> 3) & 3) * 16 + l15) * 8 + (k & 7);
            vw2frag[off] = f2bu(acc[r] * 0.0625f);  // 1/sqrt(256)
        }
    } else if (bx < 7424) {
        // ---- W1 repack: one 1KB fragment per wave, coalesced 16B/lane stores ----
        int bid = bx - 7040;           // 0..383
        int lane = t & 63;
        int fid = bid * 4 + (t >> 6);  // = nb*96 + kb
        int nb = fid / 96;
        int kb = fid - nb * 96;
        int n = nb * 16 + (lane & 15);
        int k = kb * 32 + (lane >> 4) * 8;
        short8 v;
#pragma unroll
        for (int j = 0; j < 8; j++) {
            v[j] = (short)f2bu(W1[(k + j) * 256 + n]);
        }
        *reinterpret_cast<short8*>(w1frag + ((size_t)fid * 64 + lane) * 8) = v;
    } else {
        // ---- inc bitmask ----
        int wi = bx - 7424;            // 0..15
        unsigned bits = 0u;
        int base = t * 512 + wi * 32;
#pragma unroll
        for (int b = 0; b < 32; b++) {
            if (inc_w[base + b] > 0.0f) bits |= (1u << b);
        }
        mask[wi * 256 + t] = bits;
    }
}

// ---------------------------------------------------------------------------
// K1: raw logit partials of win @ W1.  M=1568, N=256, K=3072, 8-way K-split.
// grid (49 m, 2 n, 8 k) = 784 blocks (3/CU); 4 waves = 2m x 2n; wave tile
// 16m x 64n (4 acc tiles) -> 1.25 loads/MFMA.  No bias/sigmoid (sign consumer).
__global__ __launch_bounds__(256) void gemm1_mfma(const bf16* __restrict__ win,
                                                  const unsigned short* __restrict__ w1frag,
                                                  float* __restrict__ part) {
    int t = threadIdx.x;
    int wave = t >> 6;
    int lane = t & 63;
    int quad = lane >> 4;
    int mlo = lane & 15;
    int wm = wave & 1;
    int wn = wave >> 1;
    int m0 = blockIdx.x * 32 + wm * 16;
    int nb0 = blockIdx.y * 8 + wn * 4;   // 16-wide n-tile base (0..15)
    int kz = blockIdx.z;                 // 0..7, covers k in [kz*384, kz*384+384)

    const bf16* ap = win + (m0 + mlo) * 3072 + kz * 384 + quad * 8;
    const unsigned short* bp = w1frag + lane * 8;
    int kb0 = kz * 12;

    floatx4 acc[4];
#pragma unroll
    for (int i = 0; i < 4; i++) acc[i] = (floatx4){0.f, 0.f, 0.f, 0.f};

#pragma unroll 4
    for (int kb = 0; kb < 12; kb++) {
        short8 a = *reinterpret_cast<const short8*>(ap + kb * 32);
#pragma unroll
        for (int i = 0; i < 4; i++) {
            short8 b = *reinterpret_cast<const short8*>(
                bp + ((size_t)((nb0 + i) * 96 + kb0 + kb)) * 512);
            acc[i] = __builtin_amdgcn_mfma_f32_16x16x32_bf16(a, b, acc[i], 0, 0, 0);
        }
    }

    float* pp = part + kz * 401408;
#pragma unroll
    for (int i = 0; i < 4; i++) {
        int n_g = (nb0 + i) * 16 + mlo;
#pragma unroll
        for (int r = 0; r < 4; r++) {
            int m_g = m0 + quad * 4 + r;
            pp[m_g * 256 + n_g] = acc[i][r];
        }
    }
}

// ---------------------------------------------------------------------------
// K2: clauses via bitwise AND over logit signs.  One block per window row.
// lit t included-true  <=> logit > 0;  lit 256+t  <=> logit < 0.
__global__ __launch_bounds__(256) void tm_kernel(const float* __restrict__ part,
                                                 const float* __restrict__ b1,
                                                 const unsigned* __restrict__ mask,
                                                 float* __restrict__ cl_out,
                                                 bf16* __restrict__ clauses_bf,
                                                 float* __restrict__ sum_out) {
    __shared__ unsigned g_s[16];
    __shared__ float red[4];
    int row = blockIdx.x;
    int t = threadIdx.x;
    int wave = t >> 6;
    int lane = t & 63;
    int idx = row * 256 + t;
    float L = b1[t];
#pragma unroll
    for (int s = 0; s < 8; s++) L += part[s * 401408 + idx];
    unsigned long long bhi = __ballot(L > 0.0f);  // lit t
    unsigned long long blo = __ballot(L < 0.0f);  // lit 256+t
    if (lane == 0) {
        g_s[wave * 2]         = (unsigned)bhi;
        g_s[wave * 2 + 1]     = (unsigned)(bhi >> 32);
        g_s[8 + wave * 2]     = (unsigned)blo;
        g_s[8 + wave * 2 + 1] = (unsigned)(blo >> 32);
    }
    __syncthreads();
    unsigned ok = 1u;
#pragma unroll
    for (int w = 0; w < 16; w++) {
        unsigned viol = (~g_s[w]) & mask[w * 256 + t];
        ok &= (viol == 0u) ? 1u : 0u;
    }
    float hard = (float)ok;
    cl_out[idx] = hard;
    clauses_bf[idx] = f2b(hard);
    unsigned long long cb = __ballot(ok != 0u);
    if (lane == 0) red[wave] = (float)__popcll(cb);
    __syncthreads();
    if (t == 0) sum_out[row] = (red[0] + red[1] + red[2] + red[3]) * (1.0f / 256.0f);
}

// ---------------------------------------------------------------------------
// K3: fused  feat = sigmoid(clauses @ vw2 + b2)  +  window-reverse + roll(+2,+2)
// + gated residual -> out.  M=1568, N=3072, K=256.  grid (49, 24), 4 waves
// 2m x 2n, wave tile 16m x 64n (4 acc tiles).  feat never materialized.
__global__ __launch_bounds__(256) void gemm2_out(const bf16* __restrict__ clauses_bf,
                                                 const unsigned short* __restrict__ vw2frag,
                                                 const float* __restrict__ b2v,
                                                 const float* __restrict__ x,
                                                 const float* __restrict__ gate,
                                                 float* __restrict__ out) {
    int t = threadIdx.x;
    int wave = t >> 6;
    int lane = t & 63;
    int quad = lane >> 4;
    int mlo = lane & 15;
    int wm = wave & 1;
    int wn = wave >> 1;
    int m0 = blockIdx.x * 32 + wm * 16;
    int nb0 = blockIdx.y * 8 + wn * 4;  // 16-wide n-tile base (0..191)

    const bf16* ap = clauses_bf + (m0 + mlo) * 256 + quad * 8;
    const unsigned short* bp = vw2frag + lane * 8;

    floatx4 acc[4];
#pragma unroll
    for (int i = 0; i < 4; i++) acc[i] = (floatx4){0.f, 0.f, 0.f, 0.f};

#pragma unroll
    for (int kb = 0; kb < 8; kb++) {
        short8 a = *reinterpret_cast<const short8*>(ap + kb * 32);
#pragma unroll
        for (int i = 0; i < 4; i++) {
            short8 b = *reinterpret_cast<const short8*>(
                bp + ((size_t)((nb0 + i) * 8 + kb)) * 512);
            acc[i] = __builtin_amdgcn_mfma_f32_16x16x32_bf16(a, b, acc[i], 0, 0, 0);
        }
    }

    float g = sigmoidf_(gate[0]);
    // per-r inverse window mapping: m_g -> (batch, window-h, window-w)
    int bq[4], wh[4], ww[4];
#pragma unroll
    for (int r = 0; r < 4; r++) {
        int m_g = m0 + quad * 4 + r;
        bq[r] = m_g / 196;
        int rem = m_g - bq[r] * 196;
        wh[r] = rem / 14;
        ww[r] = rem - wh[r] * 14;
    }
#pragma unroll
    for (int i = 0; i < 4; i++) {
        int n_g = (nb0 + i) * 16 + mlo;
        int cell = n_g / 192;           // 0..15 (position inside 4x4 window)
        int ch = n_g - cell * 192;      // channel
        int cellh = cell >> 2;
        int cellw = cell & 3;
        float bb = b2v[n_g];
#pragma unroll
        for (int r = 0; r < 4; r++) {
            int hh = wh[r] * 4 + cellh + 2; if (hh >= 56) hh -= 56;  // roll(+2)
            int wc = ww[r] * 4 + cellw + 2; if (wc >= 56) wc -= 56;
            int gid = ((bq[r] * 56 + hh) * 56 + wc) * 192 + ch;
            float mv = sigmoidf_(acc[i][r] + bb);
            out[gid] = x[gid] + g * mv + (1.0f - g) * sigmoidf_(mv);
        }
    }
}

// ---------------------------------------------------------------------------
extern "C" void kernel_launch(void* const* d_in, const int* in_sizes, int n_in,
                              void* d_out, int out_size, void* d_ws, size_t ws_size,
                              hipStream_t stream) {
    const float* x      = (const float*)d_in[0];
    const float* gamma  = (const float*)d_in[1];
    const float* beta   = (const float*)d_in[2];
    const float* W1     = (const float*)d_in[3];
    const float* b1     = (const float*)d_in[4];
    const float* inc_w  = (const float*)d_in[5];
    const float* vote_w = (const float*)d_in[6];
    const float* W2     = (const float*)d_in[7];
    const float* b2v    = (const float*)d_in[8];
    const float* gate   = (const float*)d_in[9];

    char* ws = (char*)d_ws;
    // workspace carve (bytes), total ~26.4 MB:
    bf16*           win        = (bf16*)(ws + 0);                  // 9,633,792
    float*          part       = (float*)(ws + 9633792);           // 12,845,056 (8x 1568*256*4)
    unsigned short* w1frag     = (unsigned short*)(ws + 22478848); // 1,572,864
    unsigned short* vw2frag    = (unsigned short*)(ws + 24051712); // 1,572,864
    bf16*           clauses_bf = (bf16*)(ws + 25624576);           //   802,816
    unsigned*       mask       = (unsigned*)(ws + 26427392);       //    16,384

    float* out     = (float*)d_out;
    float* cl_out  = out + 4816896;            // clauses: 1568*256
    float* sum_out = cl_out + 401408;          // summary: 1568

    pre_kernel<<<7440, 256, 0, stream>>>(x, gamma, beta, vote_w, W2, W1, inc_w,
                                         win, vw2frag, w1frag, mask);
    gemm1_mfma<<<dim3(49, 2, 8), 256, 0, stream>>>(win, w1frag, part);
    tm_kernel<<<1568, 256, 0, stream>>>(part, b1, mask, cl_out, clauses_bf, sum_out);
    gemm2_out<<<dim3(49, 24), 256, 0, stream>>>(clauses_bf, vw2frag, b2v, x, gate, out);
}